// Round 7
// baseline (272.771 us; speedup 1.0000x reference)
//
#include <hip/hip_runtime.h>
#include <hip/hip_fp16.h>
#include <stdint.h>

typedef _Float16 f16;
typedef f16   f16x8 __attribute__((ext_vector_type(8)));
typedef float f32x4 __attribute__((ext_vector_type(4)));

#define NTOK 262144
#define DDIM 256
#define KCB  1024
#define GG   4
#define CC   64
#define FR   4                          // 16-row fragments per wave (64 rows/wave)
#define WAVES 16                        // waves per block
#define ROWS_PER_BLK (FR * 16 * WAVES)  // 1024
#define NBLKX (NTOK / ROWS_PER_BLK)     // 256
#define NPART (NBLKX * GG)              // 1024 per-block loss partials
#define CBB   (KCB * CC * 2)            // 128 KB: full group codebook in LDS

static __device__ __forceinline__ uint32_t umin32(uint32_t a, uint32_t b) { return a < b ? a : b; }

typedef __attribute__((address_space(1))) const void gv_t;
typedef __attribute__((address_space(3))) void lv_t;
static __device__ __forceinline__ void gl_lds16(const void* g, void* l) {
    __builtin_amdgcn_global_load_lds((gv_t*)g, (lv_t*)l, 16, 0, 0);
}
static __device__ __forceinline__ void gl_lds4(const void* g, void* l) {
    __builtin_amdgcn_global_load_lds((gv_t*)g, (lv_t*)l, 4, 0, 0);
}

// ---------------- prep: fp32 codebook -> fp16 copy + (0.5 + ||e||^2) table
__global__ __launch_bounds__(64) void vq_prep(const float* __restrict__ cb,
                                              f16* __restrict__ cb16,
                                              float* __restrict__ esq05) {
    int gk = blockIdx.x;          // 0 .. G*K-1
    int c  = threadIdx.x;         // 0 .. 63
    float v = cb[(size_t)gk * CC + c];
    cb16[(size_t)gk * CC + c] = (f16)v;
    float s = v * v;
    #pragma unroll
    for (int off = 32; off; off >>= 1) s += __shfl_down(s, off, 64);
    if (c == 0) esq05[gk] = 0.5f + s;
}

// ---------------- kernel 1: whole-codebook-in-LDS, barrier-free sweep, packed-key argmin
__global__ __launch_bounds__(1024, 4) void vq_argmin(const float* __restrict__ z,
                                                     const f16* __restrict__ cb16,
                                                     const float* __restrict__ esq05,
                                                     unsigned short* __restrict__ idx,
                                                     float* __restrict__ part) {
    const int tid  = threadIdx.x;
    const int lane = tid & 63;
    const int w    = tid >> 6;                         // wave id (0..15)
    const int g    = blockIdx.y;                       // group
    const int r0   = blockIdx.x * ROWS_PER_BLK + w * (FR * 16);  // wave's base row
    const int q    = lane >> 4;                        // quarter (k-chunk selector)
    const int t    = lane & 15;                        // within-16 id

    // full group codebook (swizzled image) + e table; one block per CU (LDS-limited)
    __shared__ __align__(16) char sb[CBB + KCB * 4];
    __shared__ float ls[WAVES];

    const f16*   cbg = cb16  + (size_t)g * KCB * CC;
    const float* eg  = esq05 + (size_t)g * KCB;

    // ---- stage ENTIRE codebook once: pre-swizzled per-lane SOURCE, linear
    // global_load_lds dest (G21). LDS[code*128 + b'] = logical(code, b' ^ ((code&7)<<4)).
    #pragma unroll
    for (int c = 0; c < 8; ++c) {
        uint32_t x  = (uint32_t)(c * 16384 + w * 1024 + lane * 16);  // dest byte
        uint32_t gx = x ^ (((x >> 7) & 7u) << 4);                    // inverse-swizzled source
        gl_lds16((const char*)cbg + gx, &sb[c * 16384 + w * 1024]);  // per-lane src, uniform dest base
    }
    gl_lds4(eg + tid, &sb[CBB + w * 256]);                           // e table (4 KB)

    // ---- load A fragments (FR x 16 rows, K=64 in two 32-halves), fp32 -> fp16, scaled by -2
    // A layout for mfma_f32_16x16x32_f16: lane holds row (lane&15), k = (lane>>4)*8 + j
    f16x8 a[FR][2];
    float zsq[FR];
    #pragma unroll
    for (int f = 0; f < FR; ++f) {
        int row = r0 + f * 16 + t;
        const float* zp = z + (size_t)row * DDIM + g * CC + q * 8;
        float4 v0 = *(const float4*)(zp);
        float4 v1 = *(const float4*)(zp + 4);
        float4 v2 = *(const float4*)(zp + 32);
        float4 v3 = *(const float4*)(zp + 36);
        f16x8 a0 = { (f16)(-2.f*v0.x),(f16)(-2.f*v0.y),(f16)(-2.f*v0.z),(f16)(-2.f*v0.w),
                     (f16)(-2.f*v1.x),(f16)(-2.f*v1.y),(f16)(-2.f*v1.z),(f16)(-2.f*v1.w) };
        f16x8 a1 = { (f16)(-2.f*v2.x),(f16)(-2.f*v2.y),(f16)(-2.f*v2.z),(f16)(-2.f*v2.w),
                     (f16)(-2.f*v3.x),(f16)(-2.f*v3.y),(f16)(-2.f*v3.z),(f16)(-2.f*v3.w) };
        a[f][0] = a0; a[f][1] = a1;
        float s = v0.x*v0.x + v0.y*v0.y + v0.z*v0.z + v0.w*v0.w
                + v1.x*v1.x + v1.y*v1.y + v1.z*v1.z + v1.w*v1.w
                + v2.x*v2.x + v2.y*v2.y + v2.z*v2.z + v2.w*v2.w
                + v3.x*v3.x + v3.y*v3.y + v3.z*v3.z + v3.w*v3.w;
        s += __shfl_xor(s, 16, 64);
        s += __shfl_xor(s, 32, 64);
        zsq[f] = s;   // lane l holds full ||z_g||^2 for row (l&15)
    }

    uint32_t run[FR][4];
    #pragma unroll
    for (int f = 0; f < FR; ++f)
        #pragma unroll
        for (int i = 0; i < 4; ++i) run[f][i] = 0xFFFFFFFFu;

    // per-lane constant part of the swizzled ds_read address (b0); b1 = ^64
    const uint32_t binner = (uint32_t)t * 128 + (((uint32_t)(q * 16)) ^ (((uint32_t)(t & 7)) << 4));

    __syncthreads();      // single barrier: codebook + e staged; waves run free after this

    const float* eb = (const float*)(sb + CBB);

    // ---- barrier-free sweep over all 64 subtiles, paired for v_min3_u32
    #pragma unroll 2
    for (int s = 0; s < 64; s += 2) {
        const char* pA = sb + (size_t)s * 2048;
        f16x8 b0A = *(const f16x8*)(pA + binner);
        f16x8 b1A = *(const f16x8*)(pA + (binner ^ 64));
        f16x8 b0B = *(const f16x8*)(pA + 2048 + binner);
        f16x8 b1B = *(const f16x8*)(pA + 2048 + (binner ^ 64));
        float eA = eb[s * 16 + t];
        float eB = eb[s * 16 + 16 + t];
        f32x4 ceA = { eA, eA, eA, eA };               // d = (0.5+esq) + (-2z)·e
        f32x4 ceB = { eB, eB, eB, eB };
        uint32_t codeA = (uint32_t)(s * 16 + t);
        __builtin_amdgcn_s_setprio(1);
        #pragma unroll
        for (int f = 0; f < FR; ++f) {
            f32x4 accA = __builtin_amdgcn_mfma_f32_16x16x32_f16(a[f][0], b0A, ceA, 0, 0, 0);
            accA = __builtin_amdgcn_mfma_f32_16x16x32_f16(a[f][1], b1A, accA, 0, 0, 0);
            f32x4 accB = __builtin_amdgcn_mfma_f32_16x16x32_f16(a[f][0], b0B, ceB, 0, 0, 0);
            accB = __builtin_amdgcn_mfma_f32_16x16x32_f16(a[f][1], b1B, accB, 0, 0, 0);
            // C/D layout: col = lane&15 (code), row = (lane>>4)*4 + i
            #pragma unroll
            for (int i = 0; i < 4; ++i) {
                uint32_t kA = (__float_as_uint(accA[i]) & 0xFFFFFC00u) | codeA;        // v_and_or_b32
                uint32_t kB = (__float_as_uint(accB[i]) & 0xFFFFFC00u) | (codeA + 16); // v_and_or_b32
                run[f][i] = umin32(run[f][i], umin32(kA, kB));                         // v_min3_u32
            }
        }
        __builtin_amdgcn_s_setprio(0);
    }

    // ---- epilogue: cross-lane argmin, u16 index store, loss partials
    // R4-verified pattern: __shfl UNCONDITIONAL on all lanes; only the scalar
    // accumulate + store under the divergent (t==0) branch.
    float lsum = 0.0f;
    #pragma unroll
    for (int f = 0; f < FR; ++f) {
        #pragma unroll
        for (int i = 0; i < 4; ++i) {
            uint32_t k = run[f][i];
            k = umin32(k, __shfl_xor(k, 1, 64));
            k = umin32(k, __shfl_xor(k, 2, 64));
            k = umin32(k, __shfl_xor(k, 4, 64));
            k = umin32(k, __shfl_xor(k, 8, 64));   // 16 lanes of each quarter now agree
            int   kw     = (int)(k & 1023u);
            float minval = __uint_as_float(k & 0xFFFFFC00u) - 0.5f;  // esq - 2*dot (truncated)
            int rloc = q * 4 + i;                  // row within this 16-row fragment
            int grow = r0 + f * 16 + rloc;         // global row
            float zs = __shfl(zsq[f], rloc, 64);   // ||z_g||^2 of row rloc (held by lane rloc)
            if (t == 0) {
                idx[(grow << 2) | g] = (unsigned short)kw;
                lsum += zs + minval;               // Σ_c (zq - zg)^2 for this (row, group)
            }
        }
    }
    #pragma unroll
    for (int off = 32; off; off >>= 1) lsum += __shfl_down(lsum, off, 64);

    if (lane == 0) ls[w] = lsum;
    __syncthreads();
    if (tid == 0) {
        float s = 0.0f;
        #pragma unroll
        for (int i = 0; i < WAVES; ++i) s += ls[i];
        part[blockIdx.y * NBLKX + blockIdx.x] = s;
    }
}

// ---------------- kernel 2: gather codebook rows -> streaming fp32 output
__global__ __launch_bounds__(256) void vq_gather(const unsigned short* __restrict__ idx,
                                                 const float* __restrict__ cb32,
                                                 float* __restrict__ out) {
    const int stride = gridDim.x * 256;
    const int total  = NTOK * (DDIM / 4);              // 16.7M float4s
    for (int i = blockIdx.x * 256 + threadIdx.x; i < total; i += stride) {
        int row = i >> 6;                              // output row
        int d4  = i & 63;                              // float4 index within row
        int g   = d4 >> 4;
        int c4  = d4 & 15;
        int k   = idx[(row << 2) | g];
        float4 v = *(const float4*)(cb32 + (size_t)(((g << 10) + k) << 6) + (c4 << 2));
        *(float4*)(out + ((size_t)row << 8) + (d4 << 2)) = v;
    }
}

// ---------------- finalize: reduce per-block partials into the loss scalar
__global__ __launch_bounds__(256) void vq_final(const float* __restrict__ part,
                                                float* __restrict__ out_loss) {
    __shared__ float ls[4];
    float s = 0.0f;
    for (int i = threadIdx.x; i < NPART; i += 256) s += part[i];
    #pragma unroll
    for (int off = 32; off; off >>= 1) s += __shfl_down(s, off, 64);
    int lane = threadIdx.x & 63, w = threadIdx.x >> 6;
    if (lane == 0) ls[w] = s;
    __syncthreads();
    if (threadIdx.x == 0) {
        // loss = mean_g(BETA*commit + embed) = 1.5 * total_sq_err / (N*D)
        *out_loss = 1.5f * (ls[0] + ls[1] + ls[2] + ls[3]) * (1.0f / ((float)NTOK * (float)DDIM));
    }
}

extern "C" void kernel_launch(void* const* d_in, const int* in_sizes, int n_in,
                              void* d_out, int out_size, void* d_ws, size_t ws_size,
                              hipStream_t stream) {
    const float* z  = (const float*)d_in[0];
    const float* cb = (const float*)d_in[1];
    float* out = (float*)d_out;

    char* ws = (char*)d_ws;
    f16*   cb16  = (f16*)ws;                                             // 512 KB
    float* esq05 = (float*)(ws + (size_t)GG * KCB * CC * sizeof(f16));   // 16 KB
    float* part  = (float*)(ws + 512*1024 + 16*1024);                    // 16 KB slot
    unsigned short* idx = (unsigned short*)(ws + 512*1024 + 32*1024);    // 2 MB (u16 x N x G)

    vq_prep<<<GG * KCB, 64, 0, stream>>>(cb, cb16, esq05);

    dim3 grid(NBLKX, GG);   // 256 x 4 = 1024 blocks, 4 rounds/CU
    vq_argmin<<<grid, 1024, 0, stream>>>(z, cb16, esq05, idx, part);

    vq_gather<<<4096, 256, 0, stream>>>(idx, cb, out);

    vq_final<<<1, 256, 0, stream>>>(part, out + (size_t)NTOK * DDIM);
}

// Round 8
// 251.665 us; speedup vs baseline: 1.0839x; 1.0839x over previous
//
#include <hip/hip_runtime.h>
#include <stdint.h>

typedef int   i32x4 __attribute__((ext_vector_type(4)));
typedef int   i32x8 __attribute__((ext_vector_type(8)));
typedef float f32x16 __attribute__((ext_vector_type(16)));

#define NTOK 262144
#define DDIM 256
#define KCB  1024
#define GG   4
#define CC   64
#define WAVES 8                         // waves per block
#define ROWS_PER_BLK (WAVES * 64)       // 512 (each wave: 2 fragments x 32 rows)
#define NBLKX (NTOK / ROWS_PER_BLK)     // 512
#define NPART (NBLKX * GG)              // 2048 per-block loss partials
#define CB8B  (KCB * CC)                // 64 KB: full group codebook in fp8

static __device__ __forceinline__ uint32_t umin32(uint32_t a, uint32_t b) { return a < b ? a : b; }

typedef __attribute__((address_space(1))) const void gv_t;
typedef __attribute__((address_space(3))) void lv_t;
static __device__ __forceinline__ void gl_lds16(const void* g, void* l) {
    __builtin_amdgcn_global_load_lds((gv_t*)g, (lv_t*)l, 16, 0, 0);
}
static __device__ __forceinline__ void gl_lds4(const void* g, void* l) {
    __builtin_amdgcn_global_load_lds((gv_t*)g, (lv_t*)l, 4, 0, 0);
}

// ---------------- prep: fp32 codebook -> fp8 (x1024, e4m3) + (0.5 + ||e||^2) table
// e in +-1/K is BELOW e4m3's subnormal floor (2^-9): store e*2^10, undo via MFMA B-scale 2^-10.
__global__ __launch_bounds__(64) void vq_prep(const float* __restrict__ cb,
                                              unsigned short* __restrict__ cb8,
                                              float* __restrict__ esq05) {
    int gk = blockIdx.x;          // 0 .. G*K-1
    int c  = threadIdx.x;         // 0 .. 63
    float v = cb[(size_t)gk * CC + c];
    float s = v * v;
    #pragma unroll
    for (int off = 32; off; off >>= 1) s += __shfl_down(s, off, 64);
    if (c == 0) esq05[gk] = 0.5f + s;          // TRUE ||e||^2 (fp32, unscaled)
    if (c < 32) {
        float v0 = cb[(size_t)gk * CC + 2 * c]     * 1024.0f;
        float v1 = cb[(size_t)gk * CC + 2 * c + 1] * 1024.0f;
        int p = __builtin_amdgcn_cvt_pk_fp8_f32(v0, v1, 0, false);
        cb8[gk * 32 + c] = (unsigned short)(p & 0xFFFF);
    }
}

// ---------------- kernel 1: fp8 codebook in LDS (read-slot order), 32x32x64 MX-MFMA argmin
__global__ __launch_bounds__(512, 4) void vq_argmin(const float* __restrict__ z,
                                                    const unsigned char* __restrict__ cb8,
                                                    const float* __restrict__ esq05,
                                                    unsigned short* __restrict__ idx,
                                                    float* __restrict__ part) {
    const int tid  = threadIdx.x;
    const int lane = tid & 63;
    const int w    = tid >> 6;                   // wave id (0..7)
    const int g    = blockIdx.y;                 // group
    const int r0   = blockIdx.x * ROWS_PER_BLK + w * 64;  // wave's base row
    const int c5   = lane & 31;                  // col / row-in-fragment
    const int h    = lane >> 5;                  // k-half selector

    // codebook in fp8 (read-slot linear layout) + esq table + loss slots
    __shared__ __align__(16) char sb[CB8B + KCB * 4];
    __shared__ float ls[WAVES];

    const unsigned char* cbg8 = cb8 + (size_t)g * CB8B;
    const float*         eg   = esq05 + (size_t)g * KCB;

    // ---- stage whole codebook, laid out so ds_read is lane-sequential (0 conflicts):
    // dest chunk i (1KB = 64 lanes x 16B): subtile s=i>>1, slot=i&1;
    // lane supplies global bytes of code (s*32 + c5), k-block h, 16B half `slot`.
    #pragma unroll
    for (int i8 = 0; i8 < 8; ++i8) {
        int i = w + 8 * i8;                      // 0..63
        int s = i >> 1, slot = i & 1;
        const unsigned char* src = cbg8 + ((s * 32 + c5) * CC + h * 32 + slot * 16);
        gl_lds16(src, &sb[i * 1024]);
    }
    gl_lds4(eg + w * 64 + lane,       &sb[CB8B + w * 256]);          // esq table 4KB
    gl_lds4(eg + 512 + w * 64 + lane, &sb[CB8B + 2048 + w * 256]);

    // ---- A fragments: 2 x (32 rows x 64 dims) as fp8 (-2z), zsq in fp32
    // f8f6f4 A layout: lane holds row (lane&31), k = (lane>>5)*32 + byte j
    i32x8 a[2];
    float zsq[2];
    #pragma unroll
    for (int f = 0; f < 2; ++f) {
        const float* zp = z + (size_t)(r0 + f * 32 + c5) * DDIM + g * CC + h * 32;
        int w8[8];
        float s = 0.0f;
        #pragma unroll
        for (int j = 0; j < 8; ++j) {
            float4 v = ((const float4*)zp)[j];
            s += v.x * v.x + v.y * v.y + v.z * v.z + v.w * v.w;
            int p = __builtin_amdgcn_cvt_pk_fp8_f32(-2.0f * v.x, -2.0f * v.y, 0, false);
            p     = __builtin_amdgcn_cvt_pk_fp8_f32(-2.0f * v.z, -2.0f * v.w, p, true);
            w8[j] = p;
        }
        a[f] = (i32x8){w8[0], w8[1], w8[2], w8[3], w8[4], w8[5], w8[6], w8[7]};
        s += __shfl_xor(s, 32, 64);              // other k-half
        zsq[f] = s;                              // full ||z_g||^2 for row c5, at every lane
    }

    uint32_t run[2][16];
    #pragma unroll
    for (int f = 0; f < 2; ++f)
        #pragma unroll
        for (int r = 0; r < 16; ++r) run[f][r] = 0xFFFFFFFFu;

    __syncthreads();                             // codebook + esq staged; barrier-free afterwards

    const float* eb = (const float*)(sb + CB8B);

    // ---- sweep all 32 code-subtiles (paired): 4 MFMAs + packed-key min3 per pair
    #pragma unroll 1
    for (int s2 = 0; s2 < 32; s2 += 2) {
        const char* p0 = sb + (size_t)s2 * 2048;
        i32x4 aLo = *(const i32x4*)(p0 + lane * 16);
        i32x4 aHi = *(const i32x4*)(p0 + 1024 + lane * 16);
        i32x4 bLo = *(const i32x4*)(p0 + 2048 + lane * 16);
        i32x4 bHi = *(const i32x4*)(p0 + 3072 + lane * 16);
        i32x8 bA = (i32x8){aLo[0], aLo[1], aLo[2], aLo[3], aHi[0], aHi[1], aHi[2], aHi[3]};
        i32x8 bB = (i32x8){bLo[0], bLo[1], bLo[2], bLo[3], bHi[0], bHi[1], bHi[2], bHi[3]};
        float eA = eb[s2 * 32 + c5];
        float eB = eb[s2 * 32 + 32 + c5];
        f32x16 ceA, ceB;
        #pragma unroll
        for (int i = 0; i < 16; ++i) { ceA[i] = eA; ceB[i] = eB; }
        uint32_t codeA = (uint32_t)(s2 * 32 + c5);

        // scales: A x1 (E8M0=127 all bytes), B x2^-10 (E8M0=117 all bytes)
        __builtin_amdgcn_s_setprio(1);
        f32x16 acc00 = __builtin_amdgcn_mfma_scale_f32_32x32x64_f8f6f4(
            a[0], bA, ceA, 0, 0, 0, 0x7F7F7F7F, 0, 0x75757575);
        f32x16 acc01 = __builtin_amdgcn_mfma_scale_f32_32x32x64_f8f6f4(
            a[0], bB, ceB, 0, 0, 0, 0x7F7F7F7F, 0, 0x75757575);
        __builtin_amdgcn_s_setprio(0);
        #pragma unroll
        for (int r = 0; r < 16; ++r) {
            uint32_t kA = (__float_as_uint(acc00[r]) & 0xFFFFFC00u) | codeA;
            uint32_t kB = (__float_as_uint(acc01[r]) & 0xFFFFFC00u) | (codeA + 32u);
            run[0][r] = umin32(run[0][r], umin32(kA, kB));       // v_min3_u32
        }
        __builtin_amdgcn_s_setprio(1);
        f32x16 acc10 = __builtin_amdgcn_mfma_scale_f32_32x32x64_f8f6f4(
            a[1], bA, ceA, 0, 0, 0, 0x7F7F7F7F, 0, 0x75757575);
        f32x16 acc11 = __builtin_amdgcn_mfma_scale_f32_32x32x64_f8f6f4(
            a[1], bB, ceB, 0, 0, 0, 0x7F7F7F7F, 0, 0x75757575);
        __builtin_amdgcn_s_setprio(0);
        #pragma unroll
        for (int r = 0; r < 16; ++r) {
            uint32_t kA = (__float_as_uint(acc10[r]) & 0xFFFFFC00u) | codeA;
            uint32_t kB = (__float_as_uint(acc11[r]) & 0xFFFFFC00u) | (codeA + 32u);
            run[1][r] = umin32(run[1][r], umin32(kA, kB));
        }
    }

    // ---- epilogue: reduce keys across the 32 cols (within each lane-half),
    // store u16 idx + loss partials. Shfls UNCONDITIONAL (R5 lesson).
    float lsum = 0.0f;
    #pragma unroll
    for (int f = 0; f < 2; ++f) {
        #pragma unroll
        for (int r = 0; r < 16; ++r) {
            uint32_t k = run[f][r];
            k = umin32(k, __shfl_xor(k, 1, 64));
            k = umin32(k, __shfl_xor(k, 2, 64));
            k = umin32(k, __shfl_xor(k, 4, 64));
            k = umin32(k, __shfl_xor(k, 8, 64));
            k = umin32(k, __shfl_xor(k, 16, 64));  // 32 lanes of each half agree
            int   kw     = (int)(k & 1023u);
            float minval = __uint_as_float(k & 0xFFFFFC00u) - 0.5f;  // esq - 2*dot (truncated)
            // C/D layout (32x32): col = lane&31, row = (r&3) + 8*(r>>2) + 4*(lane>>5)
            int rloc = (r & 3) + 8 * (r >> 2) + 4 * h;
            int grow = r0 + f * 32 + rloc;
            float zs = __shfl(zsq[f], rloc, 64);   // zsq for row rloc (lanes rloc & rloc+32 agree)
            if (c5 == 0) {
                idx[(grow << 2) | g] = (unsigned short)kw;
                lsum += zs + minval;               // sum_c (zq - zg)^2 for this (row, group)
            }
        }
    }
    #pragma unroll
    for (int off = 32; off; off >>= 1) lsum += __shfl_down(lsum, off, 64);

    if (lane == 0) ls[w] = lsum;
    __syncthreads();
    if (tid == 0) {
        float s = 0.0f;
        #pragma unroll
        for (int i = 0; i < WAVES; ++i) s += ls[i];
        part[blockIdx.y * NBLKX + blockIdx.x] = s;
    }
}

// ---------------- kernel 2: gather exact fp32 codebook rows -> streaming output
__global__ __launch_bounds__(256) void vq_gather(const unsigned short* __restrict__ idx,
                                                 const float* __restrict__ cb32,
                                                 float* __restrict__ out) {
    const int stride = gridDim.x * 256;
    const int total  = NTOK * (DDIM / 4);              // 16.7M float4s
    for (int i = blockIdx.x * 256 + threadIdx.x; i < total; i += stride) {
        int row = i >> 6;                              // output row
        int d4  = i & 63;                              // float4 index within row
        int g   = d4 >> 4;
        int c4  = d4 & 15;
        int k   = idx[(row << 2) | g];
        float4 v = *(const float4*)(cb32 + (size_t)(((g << 10) + k) << 6) + (c4 << 2));
        *(float4*)(out + ((size_t)row << 8) + (d4 << 2)) = v;
    }
}

// ---------------- finalize: reduce per-block partials into the loss scalar
__global__ __launch_bounds__(256) void vq_final(const float* __restrict__ part,
                                                float* __restrict__ out_loss) {
    __shared__ float ls[4];
    float s = 0.0f;
    for (int i = threadIdx.x; i < NPART; i += 256) s += part[i];
    #pragma unroll
    for (int off = 32; off; off >>= 1) s += __shfl_down(s, off, 64);
    int lane = threadIdx.x & 63, w = threadIdx.x >> 6;
    if (lane == 0) ls[w] = s;
    __syncthreads();
    if (threadIdx.x == 0) {
        // loss = mean_g(BETA*commit + embed) = 1.5 * total_sq_err / (N*D)
        *out_loss = 1.5f * (ls[0] + ls[1] + ls[2] + ls[3]) * (1.0f / ((float)NTOK * (float)DDIM));
    }
}

extern "C" void kernel_launch(void* const* d_in, const int* in_sizes, int n_in,
                              void* d_out, int out_size, void* d_ws, size_t ws_size,
                              hipStream_t stream) {
    const float* z  = (const float*)d_in[0];
    const float* cb = (const float*)d_in[1];
    float* out = (float*)d_out;

    char* ws = (char*)d_ws;
    unsigned short* cb8 = (unsigned short*)ws;                         // 256 KB (fp8 bytes)
    float* esq05 = (float*)(ws + 256 * 1024);                          // 16 KB
    float* part  = (float*)(ws + 256 * 1024 + 16 * 1024);              // 8 KB
    unsigned short* idx = (unsigned short*)(ws + 256 * 1024 + 32 * 1024); // 2 MB

    vq_prep<<<GG * KCB, 64, 0, stream>>>(cb, cb8, esq05);

    dim3 grid(NBLKX, GG);   // 512 x 4 = 2048 blocks, 2 resident/CU
    vq_argmin<<<grid, 512, 0, stream>>>(z, (const unsigned char*)cb8, esq05, idx, part);

    vq_gather<<<4096, 256, 0, stream>>>(idx, cb, out);

    vq_final<<<1, 256, 0, stream>>>(part, out + (size_t)NTOK * DDIM);
}

// Round 9
// 239.651 us; speedup vs baseline: 1.1382x; 1.0501x over previous
//
#include <hip/hip_runtime.h>
#include <stdint.h>

typedef int   i32x4 __attribute__((ext_vector_type(4)));
typedef int   i32x8 __attribute__((ext_vector_type(8)));
typedef float f32x16 __attribute__((ext_vector_type(16)));

#define NTOK 262144
#define DDIM 256
#define KCB  1024
#define GG   4
#define CC   64
#define WAVES 4                         // waves per block
#define ROWS_PER_BLK (WAVES * 64)       // 256 (each wave: 2 fragments x 32 rows)
#define NBLKX (NTOK / ROWS_PER_BLK)     // 1024
#define NPART (NBLKX * GG)              // 4096 per-block loss partials
#define CB8B  (KCB * CC)                // 64 KB: full group codebook in fp8

static __device__ __forceinline__ uint32_t umin32(uint32_t a, uint32_t b) { return a < b ? a : b; }

typedef __attribute__((address_space(1))) const void gv_t;
typedef __attribute__((address_space(3))) void lv_t;
static __device__ __forceinline__ void gl_lds16(const void* g, void* l) {
    __builtin_amdgcn_global_load_lds((gv_t*)g, (lv_t*)l, 16, 0, 0);
}
static __device__ __forceinline__ void gl_lds4(const void* g, void* l) {
    __builtin_amdgcn_global_load_lds((gv_t*)g, (lv_t*)l, 4, 0, 0);
}

// ---------------- prep: fp32 codebook -> fp8 (x1024, e4m3) + (0.5 + ||e||^2) table
// e in +-1/K is BELOW e4m3's subnormal floor (2^-9): store e*2^10, undo via MFMA B-scale 2^-10.
__global__ __launch_bounds__(64) void vq_prep(const float* __restrict__ cb,
                                              unsigned short* __restrict__ cb8,
                                              float* __restrict__ esq05) {
    int gk = blockIdx.x;          // 0 .. G*K-1
    int c  = threadIdx.x;         // 0 .. 63
    float v = cb[(size_t)gk * CC + c];
    float s = v * v;
    #pragma unroll
    for (int off = 32; off; off >>= 1) s += __shfl_down(s, off, 64);
    if (c == 0) esq05[gk] = 0.5f + s;          // TRUE ||e||^2 (fp32, unscaled)
    if (c < 32) {
        float v0 = cb[(size_t)gk * CC + 2 * c]     * 1024.0f;
        float v1 = cb[(size_t)gk * CC + 2 * c + 1] * 1024.0f;
        int p = __builtin_amdgcn_cvt_pk_fp8_f32(v0, v1, 0, false);
        cb8[gk * 32 + c] = (unsigned short)(p & 0xFFFF);
    }
}

// ---------------- kernel 1: fp8 codebook in LDS (read-slot order), 32x32x64 MX-MFMA argmin
// 4-wave blocks, 256-reg budget (launch_bounds(256,2)): all accumulators stay in VGPRs.
__global__ __launch_bounds__(256, 2) void vq_argmin(const float* __restrict__ z,
                                                    const unsigned char* __restrict__ cb8,
                                                    const float* __restrict__ esq05,
                                                    unsigned short* __restrict__ idx,
                                                    float* __restrict__ part) {
    const int tid  = threadIdx.x;
    const int lane = tid & 63;
    const int w    = tid >> 6;                   // wave id (0..3)
    const int g    = blockIdx.y;                 // group
    const int r0   = blockIdx.x * ROWS_PER_BLK + w * 64;  // wave's base row
    const int c5   = lane & 31;                  // col / row-in-fragment
    const int h    = lane >> 5;                  // k-half selector

    // codebook in fp8 (read-slot linear layout) + esq table + loss slots
    __shared__ __align__(16) char sb[CB8B + KCB * 4];
    __shared__ float ls[WAVES];

    const unsigned char* cbg8 = cb8 + (size_t)g * CB8B;
    const float*         eg   = esq05 + (size_t)g * KCB;

    // ---- stage whole codebook, laid out so ds_read is lane-sequential (0 conflicts):
    // dest chunk i (1KB = 64 lanes x 16B): subtile s=i>>1, slot=i&1;
    // lane supplies global bytes of code (s*32 + c5), k-block h, 16B half `slot`.
    #pragma unroll
    for (int j = 0; j < 16; ++j) {
        int i = w + 4 * j;                       // 0..63
        int s = i >> 1, slot = i & 1;
        const unsigned char* src = cbg8 + ((s * 32 + c5) * CC + h * 32 + slot * 16);
        gl_lds16(src, &sb[i * 1024]);
    }
    #pragma unroll
    for (int p = 0; p < 4; ++p)                  // esq table 4KB
        gl_lds4(eg + p * 256 + tid, &sb[CB8B + p * 1024 + w * 256]);

    // ---- A fragments: 2 x (32 rows x 64 dims) as fp8 (-2z), zsq in fp32
    // f8f6f4 A layout: lane holds row (lane&31), k = (lane>>5)*32 + byte j
    i32x8 a[2];
    float zsq[2];
    #pragma unroll
    for (int f = 0; f < 2; ++f) {
        const float* zp = z + (size_t)(r0 + f * 32 + c5) * DDIM + g * CC + h * 32;
        int w8[8];
        float s = 0.0f;
        #pragma unroll
        for (int j = 0; j < 8; ++j) {
            float4 v = ((const float4*)zp)[j];
            s += v.x * v.x + v.y * v.y + v.z * v.z + v.w * v.w;
            int p = __builtin_amdgcn_cvt_pk_fp8_f32(-2.0f * v.x, -2.0f * v.y, 0, false);
            p     = __builtin_amdgcn_cvt_pk_fp8_f32(-2.0f * v.z, -2.0f * v.w, p, true);
            w8[j] = p;
        }
        a[f] = (i32x8){w8[0], w8[1], w8[2], w8[3], w8[4], w8[5], w8[6], w8[7]};
        s += __shfl_xor(s, 32, 64);              // other k-half
        zsq[f] = s;                              // full ||z_g||^2 for row c5, at every lane
    }

    uint32_t run[2][16];
    #pragma unroll
    for (int f = 0; f < 2; ++f)
        #pragma unroll
        for (int r = 0; r < 16; ++r) run[f][r] = 0xFFFFFFFFu;

    __syncthreads();                             // codebook + esq staged; barrier-free afterwards

    const float* eb = (const float*)(sb + CB8B);

    // ---- sweep all 32 code-subtiles (paired): 4 MFMAs + packed-key min3 per pair
    #pragma unroll 1
    for (int s2 = 0; s2 < 32; s2 += 2) {
        const char* p0 = sb + (size_t)s2 * 2048;
        i32x4 aLo = *(const i32x4*)(p0 + lane * 16);
        i32x4 aHi = *(const i32x4*)(p0 + 1024 + lane * 16);
        i32x4 bLo = *(const i32x4*)(p0 + 2048 + lane * 16);
        i32x4 bHi = *(const i32x4*)(p0 + 3072 + lane * 16);
        i32x8 bA = (i32x8){aLo[0], aLo[1], aLo[2], aLo[3], aHi[0], aHi[1], aHi[2], aHi[3]};
        i32x8 bB = (i32x8){bLo[0], bLo[1], bLo[2], bLo[3], bHi[0], bHi[1], bHi[2], bHi[3]};
        float eA = eb[s2 * 32 + c5];
        float eB = eb[s2 * 32 + 32 + c5];
        f32x16 ceA, ceB;
        #pragma unroll
        for (int i = 0; i < 16; ++i) { ceA[i] = eA; ceB[i] = eB; }
        uint32_t codeA = (uint32_t)(s2 * 32 + c5);

        // scales: A x1 (E8M0=127 all bytes), B x2^-10 (E8M0=117 all bytes)
        __builtin_amdgcn_s_setprio(1);
        f32x16 acc00 = __builtin_amdgcn_mfma_scale_f32_32x32x64_f8f6f4(
            a[0], bA, ceA, 0, 0, 0, 0x7F7F7F7F, 0, 0x75757575);
        f32x16 acc01 = __builtin_amdgcn_mfma_scale_f32_32x32x64_f8f6f4(
            a[0], bB, ceB, 0, 0, 0, 0x7F7F7F7F, 0, 0x75757575);
        __builtin_amdgcn_s_setprio(0);
        #pragma unroll
        for (int r = 0; r < 16; ++r) {
            uint32_t kA = (__float_as_uint(acc00[r]) & 0xFFFFFC00u) | codeA;
            uint32_t kB = (__float_as_uint(acc01[r]) & 0xFFFFFC00u) | (codeA + 32u);
            run[0][r] = umin32(run[0][r], umin32(kA, kB));       // v_min3_u32
        }
        __builtin_amdgcn_s_setprio(1);
        f32x16 acc10 = __builtin_amdgcn_mfma_scale_f32_32x32x64_f8f6f4(
            a[1], bA, ceA, 0, 0, 0, 0x7F7F7F7F, 0, 0x75757575);
        f32x16 acc11 = __builtin_amdgcn_mfma_scale_f32_32x32x64_f8f6f4(
            a[1], bB, ceB, 0, 0, 0, 0x7F7F7F7F, 0, 0x75757575);
        __builtin_amdgcn_s_setprio(0);
        #pragma unroll
        for (int r = 0; r < 16; ++r) {
            uint32_t kA = (__float_as_uint(acc10[r]) & 0xFFFFFC00u) | codeA;
            uint32_t kB = (__float_as_uint(acc11[r]) & 0xFFFFFC00u) | (codeA + 32u);
            run[1][r] = umin32(run[1][r], umin32(kA, kB));
        }
    }

    // ---- epilogue: reduce keys across the 32 cols (within each lane-half),
    // store u16 idx + loss partials. Shfls UNCONDITIONAL (R5 lesson).
    float lsum = 0.0f;
    #pragma unroll
    for (int f = 0; f < 2; ++f) {
        #pragma unroll
        for (int r = 0; r < 16; ++r) {
            uint32_t k = run[f][r];
            k = umin32(k, __shfl_xor(k, 1, 64));
            k = umin32(k, __shfl_xor(k, 2, 64));
            k = umin32(k, __shfl_xor(k, 4, 64));
            k = umin32(k, __shfl_xor(k, 8, 64));
            k = umin32(k, __shfl_xor(k, 16, 64));  // 32 lanes of each half agree
            int   kw     = (int)(k & 1023u);
            float minval = __uint_as_float(k & 0xFFFFFC00u) - 0.5f;  // esq - 2*dot (truncated)
            // C/D layout (32x32): col = lane&31, row = (r&3) + 8*(r>>2) + 4*(lane>>5)
            int rloc = (r & 3) + 8 * (r >> 2) + 4 * h;
            int grow = r0 + f * 32 + rloc;
            float zs = __shfl(zsq[f], rloc, 64);   // zsq for row rloc (lanes rloc & rloc+32 agree)
            if (c5 == 0) {
                idx[(grow << 2) | g] = (unsigned short)kw;
                lsum += zs + minval;               // sum_c (zq - zg)^2 for this (row, group)
            }
        }
    }
    #pragma unroll
    for (int off = 32; off; off >>= 1) lsum += __shfl_down(lsum, off, 64);

    if (lane == 0) ls[w] = lsum;
    __syncthreads();
    if (tid == 0) {
        float s = 0.0f;
        #pragma unroll
        for (int i = 0; i < WAVES; ++i) s += ls[i];
        part[blockIdx.y * NBLKX + blockIdx.x] = s;
    }
}

// ---------------- kernel 2: gather exact fp32 codebook rows -> streaming output
__global__ __launch_bounds__(256) void vq_gather(const unsigned short* __restrict__ idx,
                                                 const float* __restrict__ cb32,
                                                 float* __restrict__ out) {
    const int stride = gridDim.x * 256;
    const int total  = NTOK * (DDIM / 4);              // 16.7M float4s
    for (int i = blockIdx.x * 256 + threadIdx.x; i < total; i += stride) {
        int row = i >> 6;                              // output row
        int d4  = i & 63;                              // float4 index within row
        int g   = d4 >> 4;
        int c4  = d4 & 15;
        int k   = idx[(row << 2) | g];
        float4 v = *(const float4*)(cb32 + (size_t)(((g << 10) + k) << 6) + (c4 << 2));
        *(float4*)(out + ((size_t)row << 8) + (d4 << 2)) = v;
    }
}

// ---------------- finalize: reduce per-block partials into the loss scalar
__global__ __launch_bounds__(256) void vq_final(const float* __restrict__ part,
                                                float* __restrict__ out_loss) {
    __shared__ float ls[4];
    float s = 0.0f;
    for (int i = threadIdx.x; i < NPART; i += 256) s += part[i];
    #pragma unroll
    for (int off = 32; off; off >>= 1) s += __shfl_down(s, off, 64);
    int lane = threadIdx.x & 63, w = threadIdx.x >> 6;
    if (lane == 0) ls[w] = s;
    __syncthreads();
    if (threadIdx.x == 0) {
        // loss = mean_g(BETA*commit + embed) = 1.5 * total_sq_err / (N*D)
        *out_loss = 1.5f * (ls[0] + ls[1] + ls[2] + ls[3]) * (1.0f / ((float)NTOK * (float)DDIM));
    }
}

extern "C" void kernel_launch(void* const* d_in, const int* in_sizes, int n_in,
                              void* d_out, int out_size, void* d_ws, size_t ws_size,
                              hipStream_t stream) {
    const float* z  = (const float*)d_in[0];
    const float* cb = (const float*)d_in[1];
    float* out = (float*)d_out;

    char* ws = (char*)d_ws;
    unsigned short* cb8 = (unsigned short*)ws;                         // 256 KB (fp8 bytes)
    float* esq05 = (float*)(ws + 256 * 1024);                          // 16 KB
    float* part  = (float*)(ws + 256 * 1024 + 16 * 1024);              // 16 KB
    unsigned short* idx = (unsigned short*)(ws + 256 * 1024 + 32 * 1024); // 2 MB

    vq_prep<<<GG * KCB, 64, 0, stream>>>(cb, cb8, esq05);

    dim3 grid(NBLKX, GG);   // 1024 x 4 = 4096 blocks, 2 resident/CU
    vq_argmin<<<grid, 256, 0, stream>>>(z, (const unsigned char*)cb8, esq05, idx, part);

    vq_gather<<<4096, 256, 0, stream>>>(idx, cb, out);

    vq_final<<<1, 256, 0, stream>>>(part, out + (size_t)NTOK * DDIM);
}

// Round 10
// 237.769 us; speedup vs baseline: 1.1472x; 1.0079x over previous
//
#include <hip/hip_runtime.h>
#include <stdint.h>

typedef int   i32x4 __attribute__((ext_vector_type(4)));
typedef int   i32x8 __attribute__((ext_vector_type(8)));
typedef float f32x16 __attribute__((ext_vector_type(16)));

#define NTOK 262144
#define DDIM 256
#define KCB  1024
#define GG   4
#define CC   64
#define WAVES 4                         // waves per block
#define FRW  4                          // 32-row fragments per wave (128 rows/wave)
#define ROWS_PER_BLK (WAVES * FRW * 32) // 512
#define NBLKX (NTOK / ROWS_PER_BLK)     // 512
#define NPART (NBLKX * GG)              // 2048 per-block loss partials
#define CB8B  (KCB * CC)                // 64 KB: full group codebook in fp8

static __device__ __forceinline__ uint32_t umin32(uint32_t a, uint32_t b) { return a < b ? a : b; }

typedef __attribute__((address_space(1))) const void gv_t;
typedef __attribute__((address_space(3))) void lv_t;
static __device__ __forceinline__ void gl_lds16(const void* g, void* l) {
    __builtin_amdgcn_global_load_lds((gv_t*)g, (lv_t*)l, 16, 0, 0);
}
static __device__ __forceinline__ void gl_lds4(const void* g, void* l) {
    __builtin_amdgcn_global_load_lds((gv_t*)g, (lv_t*)l, 4, 0, 0);
}

// ---------------- prep: fp32 codebook -> fp8 (x1024, e4m3) + (0.5 + ||e||^2) table
// e in +-1/K is BELOW e4m3's subnormal floor (2^-9): store e*2^10, undo via MFMA B-scale 2^-10.
__global__ __launch_bounds__(64) void vq_prep(const float* __restrict__ cb,
                                              unsigned short* __restrict__ cb8,
                                              float* __restrict__ esq05) {
    int gk = blockIdx.x;          // 0 .. G*K-1
    int c  = threadIdx.x;         // 0 .. 63
    float v = cb[(size_t)gk * CC + c];
    float s = v * v;
    #pragma unroll
    for (int off = 32; off; off >>= 1) s += __shfl_down(s, off, 64);
    if (c == 0) esq05[gk] = 0.5f + s;          // TRUE ||e||^2 (fp32, unscaled)
    if (c < 32) {
        float v0 = cb[(size_t)gk * CC + 2 * c]     * 1024.0f;
        float v1 = cb[(size_t)gk * CC + 2 * c + 1] * 1024.0f;
        int p = __builtin_amdgcn_cvt_pk_fp8_f32(v0, v1, 0, false);
        cb8[gk * 32 + c] = (unsigned short)(p & 0xFFFF);
    }
}

// ---------------- kernel 1: fp8 codebook in LDS, 32x32x64 MX-MFMA argmin
// Fat waves: 4 fragments (128 rows) per wave -> each staged B-pair feeds 8 MFMAs.
__global__ __launch_bounds__(256, 2) void vq_argmin(const float* __restrict__ z,
                                                    const unsigned char* __restrict__ cb8,
                                                    const float* __restrict__ esq05,
                                                    unsigned short* __restrict__ idx,
                                                    float* __restrict__ part) {
    const int tid  = threadIdx.x;
    const int lane = tid & 63;
    const int w    = tid >> 6;                   // wave id (0..3)
    const int g    = blockIdx.y;                 // group
    const int r0   = blockIdx.x * ROWS_PER_BLK + w * (FRW * 32);  // wave's base row
    const int c5   = lane & 31;                  // col / row-in-fragment
    const int h    = lane >> 5;                  // k-half selector

    // codebook in fp8 (read-slot linear layout) + esq table + loss slots
    __shared__ __align__(16) char sb[CB8B + KCB * 4];
    __shared__ float ls[WAVES];

    const unsigned char* cbg8 = cb8 + (size_t)g * CB8B;
    const float*         eg   = esq05 + (size_t)g * KCB;

    // ---- stage whole codebook, laid out so ds_read is lane-sequential (0 conflicts):
    // dest chunk i (1KB = 64 lanes x 16B): subtile s=i>>1, slot=i&1;
    // lane supplies global bytes of code (s*32 + c5), k-block h, 16B half `slot`.
    #pragma unroll
    for (int j = 0; j < 16; ++j) {
        int i = w + 4 * j;                       // 0..63
        int s = i >> 1, slot = i & 1;
        const unsigned char* src = cbg8 + ((s * 32 + c5) * CC + h * 32 + slot * 16);
        gl_lds16(src, &sb[i * 1024]);
    }
    #pragma unroll
    for (int p = 0; p < 4; ++p)                  // esq table 4KB
        gl_lds4(eg + p * 256 + tid, &sb[CB8B + p * 1024 + w * 256]);

    // ---- A fragments: FRW x (32 rows x 64 dims) as fp8 (-2z), zsq in fp32
    // f8f6f4 A layout: lane holds row (lane&31), k = (lane>>5)*32 + byte j
    i32x8 a[FRW];
    float zsq[FRW];
    #pragma unroll
    for (int f = 0; f < FRW; ++f) {
        const float* zp = z + (size_t)(r0 + f * 32 + c5) * DDIM + g * CC + h * 32;
        int w8[8];
        float s = 0.0f;
        #pragma unroll
        for (int j = 0; j < 8; ++j) {
            float4 v = ((const float4*)zp)[j];
            s += v.x * v.x + v.y * v.y + v.z * v.z + v.w * v.w;
            int p = __builtin_amdgcn_cvt_pk_fp8_f32(-2.0f * v.x, -2.0f * v.y, 0, false);
            p     = __builtin_amdgcn_cvt_pk_fp8_f32(-2.0f * v.z, -2.0f * v.w, p, true);
            w8[j] = p;
        }
        a[f] = (i32x8){w8[0], w8[1], w8[2], w8[3], w8[4], w8[5], w8[6], w8[7]};
        s += __shfl_xor(s, 32, 64);              // other k-half
        zsq[f] = s;                              // full ||z_g||^2 for row c5, at every lane
    }

    uint32_t run[FRW][16];
    #pragma unroll
    for (int f = 0; f < FRW; ++f)
        #pragma unroll
        for (int r = 0; r < 16; ++r) run[f][r] = 0xFFFFFFFFu;

    __syncthreads();                             // codebook + esq staged; barrier-free afterwards

    const float* eb = (const float*)(sb + CB8B);

    // ---- sweep all 32 code-subtiles (paired), ds_reads prefetched one iter ahead
    i32x4 c0, c1, c2, c3;
    {
        c0 = *(const i32x4*)(sb + lane * 16);
        c1 = *(const i32x4*)(sb + 1024 + lane * 16);
        c2 = *(const i32x4*)(sb + 2048 + lane * 16);
        c3 = *(const i32x4*)(sb + 3072 + lane * 16);
    }
    #pragma unroll 1
    for (int s2 = 0; s2 < 32; s2 += 2) {
        int ns = (s2 + 2) & 31;                  // wrap -> harmless redundant load
        const char* pn = sb + (size_t)ns * 2048;
        i32x4 n0 = *(const i32x4*)(pn + lane * 16);
        i32x4 n1 = *(const i32x4*)(pn + 1024 + lane * 16);
        i32x4 n2 = *(const i32x4*)(pn + 2048 + lane * 16);
        i32x4 n3 = *(const i32x4*)(pn + 3072 + lane * 16);

        i32x8 bA = (i32x8){c0[0], c0[1], c0[2], c0[3], c1[0], c1[1], c1[2], c1[3]};
        i32x8 bB = (i32x8){c2[0], c2[1], c2[2], c2[3], c3[0], c3[1], c3[2], c3[3]};
        float eA = eb[s2 * 32 + c5];
        float eB = eb[s2 * 32 + 32 + c5];
        f32x16 ceA, ceB;
        #pragma unroll
        for (int i = 0; i < 16; ++i) { ceA[i] = eA; ceB[i] = eB; }
        uint32_t codeA = (uint32_t)(s2 * 32 + c5);

        // scales: A x1 (E8M0=127 all bytes), B x2^-10 (E8M0=117 all bytes)
        #pragma unroll
        for (int f = 0; f < FRW; ++f) {
            f32x16 accA = __builtin_amdgcn_mfma_scale_f32_32x32x64_f8f6f4(
                a[f], bA, ceA, 0, 0, 0, 0x7F7F7F7F, 0, 0x75757575);
            f32x16 accB = __builtin_amdgcn_mfma_scale_f32_32x32x64_f8f6f4(
                a[f], bB, ceB, 0, 0, 0, 0x7F7F7F7F, 0, 0x75757575);
            #pragma unroll
            for (int r = 0; r < 16; ++r) {
                uint32_t kA = (__float_as_uint(accA[r]) & 0xFFFFFC00u) | codeA;
                uint32_t kB = (__float_as_uint(accB[r]) & 0xFFFFFC00u) | (codeA + 32u);
                run[f][r] = umin32(run[f][r], umin32(kA, kB));   // v_min3_u32
            }
        }
        c0 = n0; c1 = n1; c2 = n2; c3 = n3;
    }

    // ---- epilogue: reduce keys across the 32 cols (within each lane-half),
    // store u16 idx + loss partials. Shfls UNCONDITIONAL (R5 lesson).
    float lsum = 0.0f;
    #pragma unroll
    for (int f = 0; f < FRW; ++f) {
        #pragma unroll
        for (int r = 0; r < 16; ++r) {
            uint32_t k = run[f][r];
            k = umin32(k, __shfl_xor(k, 1, 64));
            k = umin32(k, __shfl_xor(k, 2, 64));
            k = umin32(k, __shfl_xor(k, 4, 64));
            k = umin32(k, __shfl_xor(k, 8, 64));
            k = umin32(k, __shfl_xor(k, 16, 64));  // 32 lanes of each half agree
            int   kw     = (int)(k & 1023u);
            float minval = __uint_as_float(k & 0xFFFFFC00u) - 0.5f;  // esq - 2*dot (truncated)
            // C/D layout (32x32): col = lane&31, row = (r&3) + 8*(r>>2) + 4*(lane>>5)
            int rloc = (r & 3) + 8 * (r >> 2) + 4 * h;
            int grow = r0 + f * 32 + rloc;
            float zs = __shfl(zsq[f], rloc, 64);   // zsq for row rloc (lanes rloc & rloc+32 agree)
            if (c5 == 0) {
                idx[(grow << 2) | g] = (unsigned short)kw;
                lsum += zs + minval;               // sum_c (zq - zg)^2 for this (row, group)
            }
        }
    }
    #pragma unroll
    for (int off = 32; off; off >>= 1) lsum += __shfl_down(lsum, off, 64);

    if (lane == 0) ls[w] = lsum;
    __syncthreads();
    if (tid == 0) {
        float s = 0.0f;
        #pragma unroll
        for (int i = 0; i < WAVES; ++i) s += ls[i];
        part[blockIdx.y * NBLKX + blockIdx.x] = s;
    }
}

// ---------------- kernel 2: gather exact fp32 codebook rows -> streaming output
__global__ __launch_bounds__(256) void vq_gather(const unsigned short* __restrict__ idx,
                                                 const float* __restrict__ cb32,
                                                 float* __restrict__ out) {
    const int stride = gridDim.x * 256;
    const int total  = NTOK * (DDIM / 4);              // 16.7M float4s
    for (int i = blockIdx.x * 256 + threadIdx.x; i < total; i += stride) {
        int row = i >> 6;                              // output row
        int d4  = i & 63;                              // float4 index within row
        int g   = d4 >> 4;
        int c4  = d4 & 15;
        int k   = idx[(row << 2) | g];
        float4 v = *(const float4*)(cb32 + (size_t)(((g << 10) + k) << 6) + (c4 << 2));
        *(float4*)(out + ((size_t)row << 8) + (d4 << 2)) = v;
    }
}

// ---------------- finalize: reduce per-block partials into the loss scalar
__global__ __launch_bounds__(256) void vq_final(const float* __restrict__ part,
                                                float* __restrict__ out_loss) {
    __shared__ float ls[4];
    float s = 0.0f;
    for (int i = threadIdx.x; i < NPART; i += 256) s += part[i];
    #pragma unroll
    for (int off = 32; off; off >>= 1) s += __shfl_down(s, off, 64);
    int lane = threadIdx.x & 63, w = threadIdx.x >> 6;
    if (lane == 0) ls[w] = s;
    __syncthreads();
    if (threadIdx.x == 0) {
        // loss = mean_g(BETA*commit + embed) = 1.5 * total_sq_err / (N*D)
        *out_loss = 1.5f * (ls[0] + ls[1] + ls[2] + ls[3]) * (1.0f / ((float)NTOK * (float)DDIM));
    }
}

extern "C" void kernel_launch(void* const* d_in, const int* in_sizes, int n_in,
                              void* d_out, int out_size, void* d_ws, size_t ws_size,
                              hipStream_t stream) {
    const float* z  = (const float*)d_in[0];
    const float* cb = (const float*)d_in[1];
    float* out = (float*)d_out;

    char* ws = (char*)d_ws;
    unsigned short* cb8 = (unsigned short*)ws;                         // 256 KB (fp8 bytes)
    float* esq05 = (float*)(ws + 256 * 1024);                          // 16 KB
    float* part  = (float*)(ws + 256 * 1024 + 16 * 1024);              // 16 KB
    unsigned short* idx = (unsigned short*)(ws + 256 * 1024 + 32 * 1024); // 2 MB

    vq_prep<<<GG * KCB, 64, 0, stream>>>(cb, cb8, esq05);

    dim3 grid(NBLKX, GG);   // 512 x 4 = 2048 blocks, 2 resident/CU
    vq_argmin<<<grid, 256, 0, stream>>>(z, (const unsigned char*)cb8, esq05, idx, part);

    vq_gather<<<4096, 256, 0, stream>>>(idx, cb, out);

    vq_final<<<1, 256, 0, stream>>>(part, out + (size_t)NTOK * DDIM);
}